// Round 5
// baseline (296.772 us; speedup 1.0000x reference)
//
#include <hip/hip_runtime.h>

typedef short s16x8 __attribute__((ext_vector_type(8)));
typedef float f32x4 __attribute__((ext_vector_type(4)));
typedef float f32x16 __attribute__((ext_vector_type(16)));
typedef unsigned uint2v __attribute__((ext_vector_type(2)));
typedef unsigned short ushort_t;

#define CSC 0.18033688011112042f   // 0.125 * log2(e): softmax scale folded into exp2 domain

// fp32 -> bf16 round-to-nearest-even (finite inputs)
__device__ __forceinline__ ushort_t f2b(float f) {
    union { float f; unsigned int u; } c; c.f = f;
    unsigned int u = c.u;
    return (ushort_t)((u + 0x7fffu + ((u >> 16) & 1u)) >> 16);
}

__device__ __forceinline__ unsigned cvt_pk_bf16(float lo, float hi) {
    unsigned r;
    asm("v_cvt_pk_bf16_f32 %0, %1, %2" : "=v"(r) : "v"(lo), "v"(hi));
    return r;
}

__device__ __forceinline__ float asf(unsigned u) { union { unsigned u; float f; } c; c.u = u; return c.f; }
__device__ __forceinline__ unsigned asu(float f) { union { float f; unsigned u; } c; c.f = f; return c.u; }

// swaps a.hi-lanes with b.lo-lanes; for v=v: {x,y} = {own,partner(lane^32)} on every lane
__device__ __forceinline__ uint2v pl32swap(unsigned a, unsigned b) {
#if __has_builtin(__builtin_amdgcn_permlane32_swap)
    return __builtin_amdgcn_permlane32_swap(a, b, false, false);
#else
    asm volatile("v_permlane32_swap_b32 %0, %1" : "+v"(a), "+v"(b));
    uint2v r; r.x = a; r.y = b; return r;
#endif
}

__device__ __forceinline__ void gload_lds16(const void* g, void* lds) {
    __builtin_amdgcn_global_load_lds(
        (const __attribute__((address_space(1))) unsigned int*)g,
        (__attribute__((address_space(3))) unsigned int*)lds, 16, 0, 0);
}

// ---------------- fp32 -> bf16 conversion ----------------
__global__ __launch_bounds__(256) void cvt_kernel(const float* __restrict__ src,
                                                  ushort_t* __restrict__ dst, int n) {
    int i = (blockIdx.x * 256 + threadIdx.x) * 4;
    if (i >= n) return;
    float4 v = *(const float4*)&src[i];
    ushort4 o = make_ushort4(f2b(v.x), f2b(v.y), f2b(v.z), f2b(v.w));
    *(ushort4*)&dst[i] = o;
}

// ---------------- shared GEMM main loop: C[128,128] = A[M,K] * B[N,K]^T ----------------
__device__ __forceinline__ void gemm_mainloop(const ushort_t* __restrict__ A,
                                              const ushort_t* __restrict__ B,
                                              int row0, int tileN, int K,
                                              ushort_t* As, ushort_t* Bs,
                                              f32x4 acc[4][4]) {
    const int tid = threadIdx.x;
    const int lane = tid & 63;
    const int wid = tid >> 6;
    const int wrow = wid >> 1, wcol = wid & 1;

    for (int kt = 0; kt < K; kt += 32) {
        __syncthreads();
#pragma unroll
        for (int i = 0; i < 2; ++i) {
            int c = i * 256 + tid;
            int r = c >> 2, cc = c & 3;
            gload_lds16(A + (size_t)(row0 + r) * K + kt + cc * 8, As + c * 8);
            gload_lds16(B + (size_t)(tileN + r) * K + kt + cc * 8, Bs + c * 8);
        }
        __syncthreads();

        s16x8 af[4], bfr[4];
#pragma unroll
        for (int m = 0; m < 4; ++m)
            af[m] = *(const s16x8*)&As[(wrow * 64 + m * 16 + (lane & 15)) * 32 + (lane >> 4) * 8];
#pragma unroll
        for (int n = 0; n < 4; ++n)
            bfr[n] = *(const s16x8*)&Bs[(wcol * 64 + n * 16 + (lane & 15)) * 32 + (lane >> 4) * 8];
#pragma unroll
        for (int m = 0; m < 4; ++m)
#pragma unroll
            for (int n = 0; n < 4; ++n)
                acc[m][n] = __builtin_amdgcn_mfma_f32_16x16x32_bf16(af[m], bfr[n], acc[m][n], 0, 0, 0);
    }
}

// ---------------- QKV projection ----------------
// Q,K scatter to [B,H,N,64] bf16; V written TRANSPOSED to [B,H,64,N] bf16.
__global__ __launch_bounds__(256) void gemm_qkv(const ushort_t* __restrict__ X,
                                                const ushort_t* __restrict__ Wq,
                                                const ushort_t* __restrict__ Wk,
                                                const ushort_t* __restrict__ Wv,
                                                const float* __restrict__ bq,
                                                const float* __restrict__ bk,
                                                const float* __restrict__ bv,
                                                ushort_t* __restrict__ Qb,
                                                ushort_t* __restrict__ Kb,
                                                ushort_t* __restrict__ VTb) {
    __shared__ ushort_t As[128 * 32];
    __shared__ ushort_t Bs[128 * 32];
    const int K = 1024;
    const int lane = threadIdx.x & 63;
    const int wid = threadIdx.x >> 6;
    const int wrow = wid >> 1, wcol = wid & 1;
    const int row0 = blockIdx.x * 128;
    const int wsel = blockIdx.y >> 3;
    const int tileN = (blockIdx.y & 7) * 128;
    const ushort_t* B = (wsel == 0) ? Wq : (wsel == 1 ? Wk : Wv);
    const float* bias = (wsel == 0) ? bq : (wsel == 1 ? bk : bv);

    f32x4 acc[4][4] = {};
    gemm_mainloop(X, B, row0, tileN, K, As, Bs, acc);

    if (wsel == 2) {
#pragma unroll
        for (int m = 0; m < 4; ++m)
#pragma unroll
            for (int n = 0; n < 4; ++n) {
                int grow = row0 + wrow * 64 + m * 16 + (lane >> 4) * 4;
                int gcol = tileN + wcol * 64 + n * 16 + (lane & 15);
                int b = grow >> 11, nn = grow & 2047;
                int h = gcol >> 6, hd = gcol & 63;
                float bi = bias[gcol];
                ushort4 w;
                w.x = f2b(acc[m][n][0] + bi);
                w.y = f2b(acc[m][n][1] + bi);
                w.z = f2b(acc[m][n][2] + bi);
                w.w = f2b(acc[m][n][3] + bi);
                *(ushort4*)&VTb[((size_t)((b * 16 + h) * 64 + hd)) * 2048 + nn] = w;
            }
    } else {
        ushort_t* dst = (wsel == 0) ? Qb : Kb;
#pragma unroll
        for (int m = 0; m < 4; ++m)
#pragma unroll
            for (int n = 0; n < 4; ++n)
#pragma unroll
                for (int r = 0; r < 4; ++r) {
                    int grow = row0 + wrow * 64 + m * 16 + (lane >> 4) * 4 + r;
                    int gcol = tileN + wcol * 64 + n * 16 + (lane & 15);
                    float v = acc[m][n][r] + bias[gcol];
                    int b = grow >> 11, nn = grow & 2047;
                    int h = gcol >> 6, hd = gcol & 63;
                    dst[((size_t)((b * 16 + h) * 2048 + nn)) * 64 + hd] = f2b(v);
                }
    }
}

// ---------------- output projection: fp32 out + bias ----------------
__global__ __launch_bounds__(256) void gemm_out(const ushort_t* __restrict__ A,
                                                const ushort_t* __restrict__ B,
                                                const float* __restrict__ bias,
                                                float* __restrict__ out) {
    __shared__ ushort_t As[128 * 32];
    __shared__ ushort_t Bs[128 * 32];
    const int K = 1024;
    const int lane = threadIdx.x & 63;
    const int wid = threadIdx.x >> 6;
    const int wrow = wid >> 1, wcol = wid & 1;
    const int row0 = blockIdx.x * 128;
    const int tileN = blockIdx.y * 128;

    f32x4 acc[4][4] = {};
    gemm_mainloop(A, B, row0, tileN, K, As, Bs, acc);

#pragma unroll
    for (int m = 0; m < 4; ++m)
#pragma unroll
        for (int n = 0; n < 4; ++n)
#pragma unroll
            for (int r = 0; r < 4; ++r) {
                int grow = row0 + wrow * 64 + m * 16 + (lane >> 4) * 4 + r;
                int gcol = tileN + wcol * 64 + n * 16 + (lane & 15);
                out[(size_t)grow * 1024 + gcol] = acc[m][n][r] + bias[gcol];
            }
}

// ---------------- attention staging: K tile + V^T tile, source-side XOR swizzle ----------------
__device__ __forceinline__ void stage_tile(const ushort_t* __restrict__ Kg,
                                           const ushort_t* __restrict__ VTg,
                                           ushort_t* KsB, ushort_t* VsB,
                                           int k0, int tid) {
#pragma unroll
    for (int i = 0; i < 2; ++i) {
        int c = i * 256 + tid;             // 512 chunks of 16B per 8KB tile
        int r = c >> 3;                    // row 0..63
        int scc = (c & 7) ^ (r & 7);       // swizzled 16B-chunk within the row
        gload_lds16(Kg + (size_t)(k0 + r) * 64 + scc * 8, KsB + c * 8);
        gload_lds16(VTg + (size_t)r * 2048 + k0 + scc * 8, VsB + c * 8);
    }
}

// ---------------- flash attention fwd (swapped-QK^T 32x32, in-register softmax) ----------------
// grid: 512 flat blocks, XCD-chunked: xcd=fid&7 owns bh in [8*xcd, 8*xcd+8).
// block = 256 = 4 waves; wave owns 64 q-rows = TWO independent 32-row q-blocks (ILP);
// K/V LDS fragments loaded once, shared by both q-blocks. KVBLK=64; 3 buffers, 1 barrier/tile.
__global__ __launch_bounds__(256) void attn_kernel(const ushort_t* __restrict__ Qb,
                                                   const ushort_t* __restrict__ Kb,
                                                   const ushort_t* __restrict__ VTb,
                                                   ushort_t* __restrict__ Ob) {
    const int fid = blockIdx.x;
    const int xcd = fid & 7;
    const int slot = fid >> 3;                 // 0..63
    const int qtile = slot & 7;                // 8 q-tiles of 256 rows
    const int bh = (xcd << 3) + (slot >> 3);   // per-XCD K/V working set ~4MB (L2-fit)
    const int q0 = qtile * 256;
    const int tid = threadIdx.x;
    const int lane = tid & 63;
    const int wid = tid >> 6;
    const int q31 = lane & 31;
    const int hi = lane >> 5;
    const int rsw = q31 & 7;
    const int b = bh >> 4, h = bh & 15;

    const ushort_t* Q = Qb + (size_t)bh * 2048 * 64;
    const ushort_t* K = Kb + (size_t)bh * 2048 * 64;
    const ushort_t* VT = VTb + (size_t)bh * 64 * 2048;

    __shared__ ushort_t Ksh[3][64 * 64];   // K tile [k][d], chunk-swizzled content
    __shared__ ushort_t Vsh[3][64 * 64];   // V^T tile [d][k], chunk-swizzled content
    __shared__ float Al[4][2][32];         // per-wave, per-q-block alpha / inv-l redistribution

    const int qw = q0 + wid * 64;          // wave's 64 q-rows; q-block qb at qw + qb*32

    // Q B-fragments (col=q=lane&31, k-rows d = ds*16 + hi*8 + j) — resident all loop
    s16x8 qf[2][4];
#pragma unroll
    for (int qb = 0; qb < 2; ++qb)
#pragma unroll
        for (int ds = 0; ds < 4; ++ds)
            qf[qb][ds] = *(const s16x8*)&Q[(size_t)(qw + qb * 32 + q31) * 64 + ds * 16 + hi * 8];

    f32x16 o[2][2] = {};                   // O[qb][db]: rows from C-layout, d = db*32 + q31
    float m_run[2] = {-1e30f, -1e30f}, l_run[2] = {0.f, 0.f};

    stage_tile(K, VT, Ksh[0], Vsh[0], 0, tid);
    stage_tile(K, VT, Ksh[1], Vsh[1], 64, tid);

    int cur = 0, nx2 = 2;                  // buffer of tile t, buffer for tile t+2
    for (int t = 0; t < 32; ++t) {
        // drain tile t's 4 loads; tile t+1's 4 stay in flight across the barrier
        asm volatile("s_waitcnt vmcnt(4)" ::: "memory");
        __builtin_amdgcn_sched_barrier(0);
        __builtin_amdgcn_s_barrier();      // also: all waves done with body t-1 => buf nx2 free
        __builtin_amdgcn_sched_barrier(0);

        int tn = (t + 2 <= 31) ? t + 2 : 31;   // tail: dup-stage keeps vmcnt math uniform
        stage_tile(K, VT, Ksh[nx2], Vsh[nx2], tn * 64, tid);

        const ushort_t* KB = Ksh[cur];
        const ushort_t* VB = Vsh[cur];

        // ---- QK^T: S[k][q] for both q-blocks; K-frag loaded once, 2 MFMA per load ----
        f32x16 sa[2][2];                   // [qb][kb]
        sa[0][0] = (f32x16)0.f; sa[0][1] = (f32x16)0.f;
        sa[1][0] = (f32x16)0.f; sa[1][1] = (f32x16)0.f;
        __builtin_amdgcn_s_setprio(1);
#pragma unroll
        for (int kb = 0; kb < 2; ++kb)
#pragma unroll
            for (int ds = 0; ds < 4; ++ds) {
                s16x8 kfr = *(const s16x8*)&KB[(kb * 32 + q31) * 64 + (((2 * ds + hi) ^ rsw) * 8)];
                sa[0][kb] = __builtin_amdgcn_mfma_f32_32x32x16_bf16(kfr, qf[0][ds], sa[0][kb], 0, 0, 0);
                sa[1][kb] = __builtin_amdgcn_mfma_f32_32x32x16_bf16(kfr, qf[1][ds], sa[1][kb], 0, 0, 0);
            }
        __builtin_amdgcn_s_setprio(0);

        // ---- softmax (per q-block, independent chains) ----
        s16x8 pa[2][4];
#pragma unroll
        for (int qb = 0; qb < 2; ++qb) {
            // row max: max3-shaped in-lane tree + one permlane cross-half exchange
            f32x16 mx;
#pragma unroll
            for (int r = 0; r < 16; ++r) mx[r] = fmaxf(sa[qb][0][r], sa[qb][1][r]);
            float t0 = fmaxf(fmaxf(mx[0], mx[1]), mx[2]);
            float t1 = fmaxf(fmaxf(mx[3], mx[4]), mx[5]);
            float t2 = fmaxf(fmaxf(mx[6], mx[7]), mx[8]);
            float t3 = fmaxf(fmaxf(mx[9], mx[10]), mx[11]);
            float t4 = fmaxf(fmaxf(mx[12], mx[13]), mx[14]);
            float u0 = fmaxf(fmaxf(t0, t1), t2);
            float u1 = fmaxf(fmaxf(t3, t4), mx[15]);
            float tm = fmaxf(u0, u1);
            {
                uint2v w = pl32swap(asu(tm), asu(tm));
                tm = fmaxf(asf(w.x), asf(w.y));   // max(own, partner)
            }

            // defer-max rescale (T13)
            if (!__all(tm - m_run[qb] <= 40.0f)) {
                float mn = fmaxf(m_run[qb], tm);
                float alpha = exp2f((m_run[qb] - mn) * CSC);
                m_run[qb] = mn;
                l_run[qb] *= alpha;
                Al[wid][qb][q31] = alpha;          // both halves write identical value
                __builtin_amdgcn_sched_barrier(0);
                asm volatile("s_waitcnt lgkmcnt(0)" ::: "memory");
#pragma unroll
                for (int g = 0; g < 4; ++g) {
                    f32x4 av = *(const f32x4*)&Al[wid][qb][hi * 4 + g * 8];
#pragma unroll
                    for (int j = 0; j < 4; ++j) {
                        o[qb][0][g * 4 + j] *= av[j];
                        o[qb][1][g * 4 + j] *= av[j];
                    }
                }
            }

            // exp + sum + pack to PV A-fragments (in-register, T12)
            const float negmc = -m_run[qb] * CSC;
            float rs = 0.f;
#pragma unroll
            for (int kb = 0; kb < 2; ++kb) {
                float p[16];
#pragma unroll
                for (int r = 0; r < 16; ++r)
                    p[r] = exp2f(fmaf(sa[qb][kb][r], CSC, negmc));
                float s0 = ((p[0] + p[1]) + (p[2] + p[3])) + ((p[4] + p[5]) + (p[6] + p[7]));
                float s1 = ((p[8] + p[9]) + (p[10] + p[11])) + ((p[12] + p[13]) + (p[14] + p[15]));
                rs += s0 + s1;
#pragma unroll
                for (int s = 0; s < 2; ++s) {
                    unsigned a0 = cvt_pk_bf16(p[8 * s + 0], p[8 * s + 1]);
                    unsigned b0 = cvt_pk_bf16(p[8 * s + 4], p[8 * s + 5]);
                    unsigned a1 = cvt_pk_bf16(p[8 * s + 2], p[8 * s + 3]);
                    unsigned b1 = cvt_pk_bf16(p[8 * s + 6], p[8 * s + 7]);
                    uint2v w02 = pl32swap(a0, b0);   // -> word0, word2
                    uint2v w13 = pl32swap(a1, b1);   // -> word1, word3
                    union { unsigned u[4]; s16x8 v; } fr;
                    fr.u[0] = w02.x; fr.u[1] = w13.x; fr.u[2] = w02.y; fr.u[3] = w13.y;
                    pa[qb][kb * 2 + s] = fr.v;
                }
            }
            {
                uint2v w = pl32swap(asu(rs), asu(rs));
                l_run[qb] += asf(w.x) + asf(w.y);    // own + partner
            }
        }

        // ---- PV: V-frag loaded once, 2 MFMA per load ----
        __builtin_amdgcn_s_setprio(1);
#pragma unroll
        for (int s = 0; s < 4; ++s)
#pragma unroll
            for (int db = 0; db < 2; ++db) {
                s16x8 vfr = *(const s16x8*)&VB[(db * 32 + q31) * 64 + (((2 * s + hi) ^ rsw) * 8)];
                o[0][db] = __builtin_amdgcn_mfma_f32_32x32x16_bf16(pa[0][s], vfr, o[0][db], 0, 0, 0);
                o[1][db] = __builtin_amdgcn_mfma_f32_32x32x16_bf16(pa[1][s], vfr, o[1][db], 0, 0, 0);
            }
        __builtin_amdgcn_s_setprio(0);

        cur = (cur == 2) ? 0 : cur + 1;
        nx2 = (nx2 == 2) ? 0 : nx2 + 1;
    }

    // ---- epilogue: redistribute 1/l to C-layout rows, normalize, store bf16 ----
    Al[wid][0][q31] = 1.0f / l_run[0];
    Al[wid][1][q31] = 1.0f / l_run[1];
    __builtin_amdgcn_sched_barrier(0);
    asm volatile("s_waitcnt lgkmcnt(0)" ::: "memory");
#pragma unroll
    for (int qb = 0; qb < 2; ++qb)
#pragma unroll
        for (int g = 0; g < 4; ++g) {
            f32x4 iv = *(const f32x4*)&Al[wid][qb][hi * 4 + g * 8];
#pragma unroll
            for (int j = 0; j < 4; ++j) {
                int qrow = qw + qb * 32 + hi * 4 + g * 8 + j;
                size_t base = ((size_t)(b * 2048 + qrow)) * 1024 + h * 64 + q31;
#pragma unroll
                for (int db = 0; db < 2; ++db)
                    Ob[base + db * 32] = f2b(o[qb][db][g * 4 + j] * iv[j]);
            }
        }
}

// ---------------- launcher ----------------
extern "C" void kernel_launch(void* const* d_in, const int* in_sizes, int n_in,
                              void* d_out, int out_size, void* d_ws, size_t ws_size,
                              hipStream_t stream) {
    const float* x  = (const float*)d_in[0];
    const float* Wq = (const float*)d_in[1];
    const float* bq = (const float*)d_in[2];
    const float* Wk = (const float*)d_in[3];
    const float* bk = (const float*)d_in[4];
    const float* Wv = (const float*)d_in[5];
    const float* bv = (const float*)d_in[6];
    const float* Wo = (const float*)d_in[7];
    const float* bo = (const float*)d_in[8];
    float* out = (float*)d_out;

    const size_t XN = (size_t)8192 * 1024;
    const size_t WN = (size_t)1024 * 1024;

    ushort_t* Xb  = (ushort_t*)d_ws;
    ushort_t* Wqb = Xb + XN;
    ushort_t* Wkb = Wqb + WN;
    ushort_t* Wvb = Wkb + WN;
    ushort_t* Wob = Wvb + WN;
    ushort_t* Qb  = Wob + WN;
    ushort_t* Kb  = Qb + XN;
    ushort_t* VTb = Kb + XN;   // V transposed: [B,H,64,2048]
    ushort_t* Ob  = VTb + XN;

    cvt_kernel<<<(int)(XN / 4 / 256), 256, 0, stream>>>(x, Xb, (int)XN);
    cvt_kernel<<<(int)(WN / 4 / 256), 256, 0, stream>>>(Wq, Wqb, (int)WN);
    cvt_kernel<<<(int)(WN / 4 / 256), 256, 0, stream>>>(Wk, Wkb, (int)WN);
    cvt_kernel<<<(int)(WN / 4 / 256), 256, 0, stream>>>(Wv, Wvb, (int)WN);
    cvt_kernel<<<(int)(WN / 4 / 256), 256, 0, stream>>>(Wo, Wob, (int)WN);

    dim3 g1(64, 24);
    gemm_qkv<<<g1, 256, 0, stream>>>(Xb, Wqb, Wkb, Wvb, bq, bk, bv, Qb, Kb, VTb);

    attn_kernel<<<512, 256, 0, stream>>>(Qb, Kb, VTb, Ob);

    dim3 g3(64, 8);
    gemm_out<<<g3, 256, 0, stream>>>(Ob, Wob, bo, out);
}

// Round 6
// 241.486 us; speedup vs baseline: 1.2289x; 1.2289x over previous
//
#include <hip/hip_runtime.h>

typedef short s16x8 __attribute__((ext_vector_type(8)));
typedef float f32x4 __attribute__((ext_vector_type(4)));
typedef float f32x16 __attribute__((ext_vector_type(16)));
typedef unsigned uint2v __attribute__((ext_vector_type(2)));
typedef unsigned short ushort_t;

#define CSC 0.18033688011112042f   // 0.125 * log2(e): softmax scale folded into exp2 domain

// fp32 -> bf16 round-to-nearest-even (finite inputs)
__device__ __forceinline__ ushort_t f2b(float f) {
    union { float f; unsigned int u; } c; c.f = f;
    unsigned int u = c.u;
    return (ushort_t)((u + 0x7fffu + ((u >> 16) & 1u)) >> 16);
}

__device__ __forceinline__ unsigned cvt_pk_bf16(float lo, float hi) {
    unsigned r;
    asm("v_cvt_pk_bf16_f32 %0, %1, %2" : "=v"(r) : "v"(lo), "v"(hi));
    return r;
}

__device__ __forceinline__ float asf(unsigned u) { union { unsigned u; float f; } c; c.u = u; return c.f; }
__device__ __forceinline__ unsigned asu(float f) { union { float f; unsigned u; } c; c.f = f; return c.u; }

// swaps a.hi-lanes with b.lo-lanes; for v=v: {x,y} = {own,partner(lane^32)} on every lane
__device__ __forceinline__ uint2v pl32swap(unsigned a, unsigned b) {
#if __has_builtin(__builtin_amdgcn_permlane32_swap)
    return __builtin_amdgcn_permlane32_swap(a, b, false, false);
#else
    asm volatile("v_permlane32_swap_b32 %0, %1" : "+v"(a), "+v"(b));
    uint2v r; r.x = a; r.y = b; return r;
#endif
}

__device__ __forceinline__ void gload_lds16(const void* g, void* lds) {
    __builtin_amdgcn_global_load_lds(
        (const __attribute__((address_space(1))) unsigned int*)g,
        (__attribute__((address_space(3))) unsigned int*)lds, 16, 0, 0);
}

// ---------------- fp32 -> bf16 conversion ----------------
__global__ __launch_bounds__(256) void cvt_kernel(const float* __restrict__ src,
                                                  ushort_t* __restrict__ dst, int n) {
    int i = (blockIdx.x * 256 + threadIdx.x) * 4;
    if (i >= n) return;
    float4 v = *(const float4*)&src[i];
    ushort4 o = make_ushort4(f2b(v.x), f2b(v.y), f2b(v.z), f2b(v.w));
    *(ushort4*)&dst[i] = o;
}

// ---------------- shared GEMM main loop: C[128,128] = A[M,K] * B[N,K]^T ----------------
__device__ __forceinline__ void gemm_mainloop(const ushort_t* __restrict__ A,
                                              const ushort_t* __restrict__ B,
                                              int row0, int tileN, int K,
                                              ushort_t* As, ushort_t* Bs,
                                              f32x4 acc[4][4]) {
    const int tid = threadIdx.x;
    const int lane = tid & 63;
    const int wid = tid >> 6;
    const int wrow = wid >> 1, wcol = wid & 1;

    for (int kt = 0; kt < K; kt += 32) {
        __syncthreads();
#pragma unroll
        for (int i = 0; i < 2; ++i) {
            int c = i * 256 + tid;
            int r = c >> 2, cc = c & 3;
            gload_lds16(A + (size_t)(row0 + r) * K + kt + cc * 8, As + c * 8);
            gload_lds16(B + (size_t)(tileN + r) * K + kt + cc * 8, Bs + c * 8);
        }
        __syncthreads();

        s16x8 af[4], bfr[4];
#pragma unroll
        for (int m = 0; m < 4; ++m)
            af[m] = *(const s16x8*)&As[(wrow * 64 + m * 16 + (lane & 15)) * 32 + (lane >> 4) * 8];
#pragma unroll
        for (int n = 0; n < 4; ++n)
            bfr[n] = *(const s16x8*)&Bs[(wcol * 64 + n * 16 + (lane & 15)) * 32 + (lane >> 4) * 8];
#pragma unroll
        for (int m = 0; m < 4; ++m)
#pragma unroll
            for (int n = 0; n < 4; ++n)
                acc[m][n] = __builtin_amdgcn_mfma_f32_16x16x32_bf16(af[m], bfr[n], acc[m][n], 0, 0, 0);
    }
}

// ---------------- QKV projection ----------------
// Q,K scatter to [B,H,N,64] bf16; V written TRANSPOSED to [B,H,64,N] bf16.
__global__ __launch_bounds__(256) void gemm_qkv(const ushort_t* __restrict__ X,
                                                const ushort_t* __restrict__ Wq,
                                                const ushort_t* __restrict__ Wk,
                                                const ushort_t* __restrict__ Wv,
                                                const float* __restrict__ bq,
                                                const float* __restrict__ bk,
                                                const float* __restrict__ bv,
                                                ushort_t* __restrict__ Qb,
                                                ushort_t* __restrict__ Kb,
                                                ushort_t* __restrict__ VTb) {
    __shared__ ushort_t As[128 * 32];
    __shared__ ushort_t Bs[128 * 32];
    const int K = 1024;
    const int lane = threadIdx.x & 63;
    const int wid = threadIdx.x >> 6;
    const int wrow = wid >> 1, wcol = wid & 1;
    const int row0 = blockIdx.x * 128;
    const int wsel = blockIdx.y >> 3;
    const int tileN = (blockIdx.y & 7) * 128;
    const ushort_t* B = (wsel == 0) ? Wq : (wsel == 1 ? Wk : Wv);
    const float* bias = (wsel == 0) ? bq : (wsel == 1 ? bk : bv);

    f32x4 acc[4][4] = {};
    gemm_mainloop(X, B, row0, tileN, K, As, Bs, acc);

    if (wsel == 2) {
#pragma unroll
        for (int m = 0; m < 4; ++m)
#pragma unroll
            for (int n = 0; n < 4; ++n) {
                int grow = row0 + wrow * 64 + m * 16 + (lane >> 4) * 4;
                int gcol = tileN + wcol * 64 + n * 16 + (lane & 15);
                int b = grow >> 11, nn = grow & 2047;
                int h = gcol >> 6, hd = gcol & 63;
                float bi = bias[gcol];
                ushort4 w;
                w.x = f2b(acc[m][n][0] + bi);
                w.y = f2b(acc[m][n][1] + bi);
                w.z = f2b(acc[m][n][2] + bi);
                w.w = f2b(acc[m][n][3] + bi);
                *(ushort4*)&VTb[((size_t)((b * 16 + h) * 64 + hd)) * 2048 + nn] = w;
            }
    } else {
        ushort_t* dst = (wsel == 0) ? Qb : Kb;
#pragma unroll
        for (int m = 0; m < 4; ++m)
#pragma unroll
            for (int n = 0; n < 4; ++n)
#pragma unroll
                for (int r = 0; r < 4; ++r) {
                    int grow = row0 + wrow * 64 + m * 16 + (lane >> 4) * 4 + r;
                    int gcol = tileN + wcol * 64 + n * 16 + (lane & 15);
                    float v = acc[m][n][r] + bias[gcol];
                    int b = grow >> 11, nn = grow & 2047;
                    int h = gcol >> 6, hd = gcol & 63;
                    dst[((size_t)((b * 16 + h) * 2048 + nn)) * 64 + hd] = f2b(v);
                }
    }
}

// ---------------- output projection: fp32 out + bias ----------------
__global__ __launch_bounds__(256) void gemm_out(const ushort_t* __restrict__ A,
                                                const ushort_t* __restrict__ B,
                                                const float* __restrict__ bias,
                                                float* __restrict__ out) {
    __shared__ ushort_t As[128 * 32];
    __shared__ ushort_t Bs[128 * 32];
    const int K = 1024;
    const int lane = threadIdx.x & 63;
    const int wid = threadIdx.x >> 6;
    const int wrow = wid >> 1, wcol = wid & 1;
    const int row0 = blockIdx.x * 128;
    const int tileN = blockIdx.y * 128;

    f32x4 acc[4][4] = {};
    gemm_mainloop(A, B, row0, tileN, K, As, Bs, acc);

#pragma unroll
    for (int m = 0; m < 4; ++m)
#pragma unroll
        for (int n = 0; n < 4; ++n)
#pragma unroll
            for (int r = 0; r < 4; ++r) {
                int grow = row0 + wrow * 64 + m * 16 + (lane >> 4) * 4 + r;
                int gcol = tileN + wcol * 64 + n * 16 + (lane & 15);
                out[(size_t)grow * 1024 + gcol] = acc[m][n][r] + bias[gcol];
            }
}

// ---------------- attention staging: K tile + V^T tile, source-side XOR swizzle ----------------
// 512 threads: each thread stages exactly one 16B chunk of K and one of V^T per tile.
__device__ __forceinline__ void stage_tile(const ushort_t* __restrict__ Kg,
                                           const ushort_t* __restrict__ VTg,
                                           ushort_t* KsB, ushort_t* VsB,
                                           int k0, int tid) {
    int r = tid >> 3;                  // row 0..63
    int scc = (tid & 7) ^ (r & 7);     // swizzled 16B-chunk within the row
    gload_lds16(Kg + (size_t)(k0 + r) * 64 + scc * 8, KsB + tid * 8);
    gload_lds16(VTg + (size_t)r * 2048 + k0 + scc * 8, VsB + tid * 8);
}

// ---------------- flash attention fwd (swapped-QK^T 32x32, in-register softmax) ----------------
// grid: 512 flat blocks of 512 threads (8 waves), XCD-chunked: xcd=fid&7 owns bh in [8*xcd,8*xcd+8).
// Each wave owns 32 q-rows (round-4 body); block covers 256 q-rows; 2 blocks/CU resident in ONE
// generation => 4 waves/SIMD TLP (round-4 had ~2). KVBLK=64; 3 LDS buffers, 1 barrier/tile.
__global__ __launch_bounds__(512, 4) void attn_kernel(const ushort_t* __restrict__ Qb,
                                                      const ushort_t* __restrict__ Kb,
                                                      const ushort_t* __restrict__ VTb,
                                                      ushort_t* __restrict__ Ob) {
    const int fid = blockIdx.x;
    const int xcd = fid & 7;
    const int slot = fid >> 3;                 // 0..63
    const int qtile = slot & 7;                // 8 q-tiles of 256 rows
    const int bh = (xcd << 3) + (slot >> 3);   // per-XCD K/V working set ~4MB (L2-fit)
    const int q0 = qtile * 256;
    const int tid = threadIdx.x;
    const int lane = tid & 63;
    const int wid = tid >> 6;                  // 0..7
    const int q31 = lane & 31;
    const int hi = lane >> 5;
    const int rsw = q31 & 7;
    const int b = bh >> 4, h = bh & 15;

    const ushort_t* Q = Qb + (size_t)bh * 2048 * 64;
    const ushort_t* K = Kb + (size_t)bh * 2048 * 64;
    const ushort_t* VT = VTb + (size_t)bh * 64 * 2048;

    __shared__ ushort_t Ksh[3][64 * 64];   // K tile [k][d], chunk-swizzled content
    __shared__ ushort_t Vsh[3][64 * 64];   // V^T tile [d][k], chunk-swizzled content
    __shared__ float Al[8][32];            // per-wave alpha / inv-l redistribution

    const int qw = q0 + wid * 32;

    // Q B-fragments (col=q=lane&31, k-rows d = ds*16 + hi*8 + j) — resident all loop
    s16x8 qf[4];
#pragma unroll
    for (int ds = 0; ds < 4; ++ds)
        qf[ds] = *(const s16x8*)&Q[(size_t)(qw + q31) * 64 + ds * 16 + hi * 8];

    f32x16 o[2] = {};          // O[q-rows][d = db*32 + q31]
    float m_run = -1e30f, l_run = 0.f;

    stage_tile(K, VT, Ksh[0], Vsh[0], 0, tid);
    stage_tile(K, VT, Ksh[1], Vsh[1], 64, tid);

    int cur = 0, nx2 = 2;      // buffer of tile t, buffer for tile t+2
    for (int t = 0; t < 32; ++t) {
        // drain tile t's 2 loads; tile t+1's 2 stay in flight across the barrier
        asm volatile("s_waitcnt vmcnt(2)" ::: "memory");
        __builtin_amdgcn_sched_barrier(0);
        __builtin_amdgcn_s_barrier();      // also: all waves done with body t-1 => buf nx2 free
        __builtin_amdgcn_sched_barrier(0);

        int tn = (t + 2 <= 31) ? t + 2 : 31;   // tail: dup-stage keeps vmcnt math uniform
        stage_tile(K, VT, Ksh[nx2], Vsh[nx2], tn * 64, tid);

        const ushort_t* KB = Ksh[cur];
        const ushort_t* VB = Vsh[cur];

        // ---- QK^T: S[k][q], A = K-frag (row k = kb*32 + lane&31), B = Q-frag ----
        f32x16 sa[2];
        sa[0] = (f32x16)0.f; sa[1] = (f32x16)0.f;
        __builtin_amdgcn_s_setprio(1);
#pragma unroll
        for (int kb = 0; kb < 2; ++kb)
#pragma unroll
            for (int ds = 0; ds < 4; ++ds) {
                s16x8 kfr = *(const s16x8*)&KB[(kb * 32 + q31) * 64 + (((2 * ds + hi) ^ rsw) * 8)];
                sa[kb] = __builtin_amdgcn_mfma_f32_32x32x16_bf16(kfr, qf[ds], sa[kb], 0, 0, 0);
            }
        __builtin_amdgcn_s_setprio(0);

        // ---- row max (max3-shaped in-lane tree + one permlane cross-half exchange) ----
        f32x16 mx;
#pragma unroll
        for (int r = 0; r < 16; ++r) mx[r] = fmaxf(sa[0][r], sa[1][r]);
        float t0 = fmaxf(fmaxf(mx[0], mx[1]), mx[2]);
        float t1 = fmaxf(fmaxf(mx[3], mx[4]), mx[5]);
        float t2 = fmaxf(fmaxf(mx[6], mx[7]), mx[8]);
        float t3 = fmaxf(fmaxf(mx[9], mx[10]), mx[11]);
        float t4 = fmaxf(fmaxf(mx[12], mx[13]), mx[14]);
        float u0 = fmaxf(fmaxf(t0, t1), t2);
        float u1 = fmaxf(fmaxf(t3, t4), mx[15]);
        float tm = fmaxf(u0, u1);
        {
            uint2v w = pl32swap(asu(tm), asu(tm));
            tm = fmaxf(asf(w.x), asf(w.y));   // max(own, partner)
        }

        // ---- defer-max rescale (T13) ----
        if (!__all(tm - m_run <= 40.0f)) {
            float mn = fmaxf(m_run, tm);
            float alpha = exp2f((m_run - mn) * CSC);
            m_run = mn;
            l_run *= alpha;
            Al[wid][q31] = alpha;          // both halves write identical value
            __builtin_amdgcn_sched_barrier(0);
            asm volatile("s_waitcnt lgkmcnt(0)" ::: "memory");
#pragma unroll
            for (int g = 0; g < 4; ++g) {
                f32x4 av = *(const f32x4*)&Al[wid][hi * 4 + g * 8];
#pragma unroll
                for (int j = 0; j < 4; ++j) {
                    o[0][g * 4 + j] *= av[j];
                    o[1][g * 4 + j] *= av[j];
                }
            }
        }

        // ---- exp + sum + pack to PV A-fragments (in-register, T12) ----
        const float negmc = -m_run * CSC;
        s16x8 pa[4];
        float rs = 0.f;
#pragma unroll
        for (int kb = 0; kb < 2; ++kb) {
            float p[16];
#pragma unroll
            for (int r = 0; r < 16; ++r)
                p[r] = exp2f(fmaf(sa[kb][r], CSC, negmc));
            float s0 = ((p[0] + p[1]) + (p[2] + p[3])) + ((p[4] + p[5]) + (p[6] + p[7]));
            float s1 = ((p[8] + p[9]) + (p[10] + p[11])) + ((p[12] + p[13]) + (p[14] + p[15]));
            rs += s0 + s1;
#pragma unroll
            for (int s = 0; s < 2; ++s) {
                unsigned a0 = cvt_pk_bf16(p[8 * s + 0], p[8 * s + 1]);
                unsigned b0 = cvt_pk_bf16(p[8 * s + 4], p[8 * s + 5]);
                unsigned a1 = cvt_pk_bf16(p[8 * s + 2], p[8 * s + 3]);
                unsigned b1 = cvt_pk_bf16(p[8 * s + 6], p[8 * s + 7]);
                uint2v w02 = pl32swap(a0, b0);   // -> word0, word2
                uint2v w13 = pl32swap(a1, b1);   // -> word1, word3
                union { unsigned u[4]; s16x8 v; } fr;
                fr.u[0] = w02.x; fr.u[1] = w13.x; fr.u[2] = w02.y; fr.u[3] = w13.y;
                pa[kb * 2 + s] = fr.v;
            }
        }
        {
            uint2v w = pl32swap(asu(rs), asu(rs));
            l_run += asf(w.x) + asf(w.y);     // own + partner
        }

        // ---- PV: O[q][d] += P * V, B = V^T-frag (col d = lane&31, k-rows = s*16+hi*8+j) ----
        __builtin_amdgcn_s_setprio(1);
#pragma unroll
        for (int s = 0; s < 4; ++s)
#pragma unroll
            for (int db = 0; db < 2; ++db) {
                s16x8 vfr = *(const s16x8*)&VB[(db * 32 + q31) * 64 + (((2 * s + hi) ^ rsw) * 8)];
                o[db] = __builtin_amdgcn_mfma_f32_32x32x16_bf16(pa[s], vfr, o[db], 0, 0, 0);
            }
        __builtin_amdgcn_s_setprio(0);

        cur = (cur == 2) ? 0 : cur + 1;
        nx2 = (nx2 == 2) ? 0 : nx2 + 1;
    }

    // ---- epilogue: redistribute 1/l to C-layout rows, normalize, store bf16 ----
    Al[wid][q31] = 1.0f / l_run;     // per-wave row: no cross-wave hazard
    __builtin_amdgcn_sched_barrier(0);
    asm volatile("s_waitcnt lgkmcnt(0)" ::: "memory");
#pragma unroll
    for (int g = 0; g < 4; ++g) {
        f32x4 iv = *(const f32x4*)&Al[wid][hi * 4 + g * 8];
#pragma unroll
        for (int j = 0; j < 4; ++j) {
            int qrow = qw + hi * 4 + g * 8 + j;
            size_t base = ((size_t)(b * 2048 + qrow)) * 1024 + h * 64 + q31;
#pragma unroll
            for (int db = 0; db < 2; ++db)
                Ob[base + db * 32] = f2b(o[db][g * 4 + j] * iv[j]);
        }
    }
}

// ---------------- launcher ----------------
extern "C" void kernel_launch(void* const* d_in, const int* in_sizes, int n_in,
                              void* d_out, int out_size, void* d_ws, size_t ws_size,
                              hipStream_t stream) {
    const float* x  = (const float*)d_in[0];
    const float* Wq = (const float*)d_in[1];
    const float* bq = (const float*)d_in[2];
    const float* Wk = (const float*)d_in[3];
    const float* bk = (const float*)d_in[4];
    const float* Wv = (const float*)d_in[5];
    const float* bv = (const float*)d_in[6];
    const float* Wo = (const float*)d_in[7];
    const float* bo = (const float*)d_in[8];
    float* out = (float*)d_out;

    const size_t XN = (size_t)8192 * 1024;
    const size_t WN = (size_t)1024 * 1024;

    ushort_t* Xb  = (ushort_t*)d_ws;
    ushort_t* Wqb = Xb + XN;
    ushort_t* Wkb = Wqb + WN;
    ushort_t* Wvb = Wkb + WN;
    ushort_t* Wob = Wvb + WN;
    ushort_t* Qb  = Wob + WN;
    ushort_t* Kb  = Qb + XN;
    ushort_t* VTb = Kb + XN;   // V transposed: [B,H,64,2048]
    ushort_t* Ob  = VTb + XN;

    cvt_kernel<<<(int)(XN / 4 / 256), 256, 0, stream>>>(x, Xb, (int)XN);
    cvt_kernel<<<(int)(WN / 4 / 256), 256, 0, stream>>>(Wq, Wqb, (int)WN);
    cvt_kernel<<<(int)(WN / 4 / 256), 256, 0, stream>>>(Wk, Wkb, (int)WN);
    cvt_kernel<<<(int)(WN / 4 / 256), 256, 0, stream>>>(Wv, Wvb, (int)WN);
    cvt_kernel<<<(int)(WN / 4 / 256), 256, 0, stream>>>(Wo, Wob, (int)WN);

    dim3 g1(64, 24);
    gemm_qkv<<<g1, 256, 0, stream>>>(Xb, Wqb, Wkb, Wvb, bq, bk, bv, Qb, Kb, VTb);

    attn_kernel<<<512, 512, 0, stream>>>(Qb, Kb, VTb, Ob);

    dim3 g3(64, 8);
    gemm_out<<<g3, 256, 0, stream>>>(Ob, Wob, bo, out);
}